// Round 1
// baseline (389.803 us; speedup 1.0000x reference)
//
#include <hip/hip_runtime.h>
#include <stdint.h>

// ---------------------------------------------------------------------------
// Problem constants (shapes fixed by the reference)
//   E=64 H=64 PRE1=512 BNK=1024 S=256 P=16 B=4096
// Dead code: vx/vy/W_vel/b_vel/Wa1/Wa2 + all attention BN params -- softmax
// over a size-1 axis is identically 1.0, so w==1 and x = concat*0.05.
// ---------------------------------------------------------------------------

typedef __bf16 bf16x8 __attribute__((ext_vector_type(8)));
typedef float  f32x4  __attribute__((ext_vector_type(4)));

// workspace layout (bytes)
#define BP1_OFF 0               // Wp1 packed bf16: 32 ntiles * 4 kblk * 64 * 8  = 131072 B
#define BP2_OFF 131072          // Wp2 packed bf16: 64 ntiles * 16 kblk * 64 * 8 = 1048576 B
#define A1_OFF  1179648         // 512 f32
#define C1_OFF  1181696         // 512 f32
#define A2_OFF  1183744         // 1024 f32
#define C2_OFF  1187840         // 1024 f32
#define SW_OFF  1191936         // 192 f32: SW0[64] SW1[64] SB[64] (0.05 folded)
// total ws needed: 1192704 bytes

__device__ __forceinline__ unsigned short f2bf(float f) {
    union { float f; unsigned int u; } c; c.f = f;
    unsigned int u = c.u;
    return (unsigned short)((u + 0x7fffu + ((u >> 16) & 1u)) >> 16);
}

// ---------------------------------------------------------------------------
// Prep: pack weights into MFMA B-fragment order and fold bias+BN.
// B-frag layout for 16x16x32: lane l needs B[k = kb*32 + (l>>4)*8 + j][n = nt*16 + (l&15)]
// packed at ((nt*KB + kb)*64 + l)*8 contiguous bf16 -> 16B per lane, coalesced.
// ---------------------------------------------------------------------------
__global__ void prep_kernel(
    const float* __restrict__ Wsp,  const float* __restrict__ bsp,
    const float* __restrict__ Wp1,  const float* __restrict__ bp1,
    const float* __restrict__ gp1,  const float* __restrict__ btp1,
    const float* __restrict__ mp1,  const float* __restrict__ vp1,
    const float* __restrict__ Wp2,  const float* __restrict__ bp2,
    const float* __restrict__ gp2,  const float* __restrict__ btp2,
    const float* __restrict__ mp2,  const float* __restrict__ vp2,
    unsigned char* __restrict__ ws)
{
    int t = blockIdx.x * 256 + threadIdx.x;

    if (t < 65536) {
        // Bpack2: N=1024 (64 ntiles), K=512 (16 kblocks)
        int nt = t >> 10, kb = (t >> 6) & 15, l = t & 63;
        int n  = nt * 16 + (l & 15);
        int k0 = kb * 32 + (l >> 4) * 8;
        unsigned int w0, w1, w2, w3;
        w0 = f2bf(Wp2[(k0+0)*1024+n]) | ((unsigned)f2bf(Wp2[(k0+1)*1024+n]) << 16);
        w1 = f2bf(Wp2[(k0+2)*1024+n]) | ((unsigned)f2bf(Wp2[(k0+3)*1024+n]) << 16);
        w2 = f2bf(Wp2[(k0+4)*1024+n]) | ((unsigned)f2bf(Wp2[(k0+5)*1024+n]) << 16);
        w3 = f2bf(Wp2[(k0+6)*1024+n]) | ((unsigned)f2bf(Wp2[(k0+7)*1024+n]) << 16);
        uint4* dst = (uint4*)(ws + BP2_OFF) + t;
        uint4 v; v.x = w0; v.y = w1; v.z = w2; v.w = w3;
        *dst = v;
    } else if (t < 65536 + 8192) {
        // Bpack1: N=512 (32 ntiles), K=128 (4 kblocks)
        int q = t - 65536;
        int nt = q >> 8, kb = (q >> 6) & 3, l = q & 63;
        int n  = nt * 16 + (l & 15);
        int k0 = kb * 32 + (l >> 4) * 8;
        unsigned int w0, w1, w2, w3;
        w0 = f2bf(Wp1[(k0+0)*512+n]) | ((unsigned)f2bf(Wp1[(k0+1)*512+n]) << 16);
        w1 = f2bf(Wp1[(k0+2)*512+n]) | ((unsigned)f2bf(Wp1[(k0+3)*512+n]) << 16);
        w2 = f2bf(Wp1[(k0+4)*512+n]) | ((unsigned)f2bf(Wp1[(k0+5)*512+n]) << 16);
        w3 = f2bf(Wp1[(k0+6)*512+n]) | ((unsigned)f2bf(Wp1[(k0+7)*512+n]) << 16);
        uint4* dst = (uint4*)(ws + BP1_OFF) + q;
        uint4 v; v.x = w0; v.y = w1; v.z = w2; v.w = w3;
        *dst = v;
    } else if (t < 65536 + 8192 + 1024) {
        // BN2 fold: y2 = (acc + bp2 - mp2)*g*rsqrt(v+eps) + bt  ->  acc*A2 + C2
        int n = t - 73728;
        float a = gp2[n] * rsqrtf(vp2[n] + 1e-5f);
        ((float*)(ws + A2_OFF))[n] = a;
        ((float*)(ws + C2_OFF))[n] = btp2[n] + (bp2[n] - mp2[n]) * a;
    } else if (t < 65536 + 8192 + 1024 + 512) {
        int n = t - 74752;
        float a = gp1[n] * rsqrtf(vp1[n] + 1e-5f);
        ((float*)(ws + A1_OFF))[n] = a;
        ((float*)(ws + C1_OFF))[n] = btp1[n] + (bp1[n] - mp1[n]) * a;
    } else if (t < 65536 + 8192 + 1024 + 512 + 64) {
        int c = t - 75264;
        float* SWb = (float*)(ws + SW_OFF);
        SWb[c]       = 0.05f * Wsp[c];        // W_sp[0][c]
        SWb[64 + c]  = 0.05f * Wsp[64 + c];   // W_sp[1][c]
        SWb[128 + c] = 0.05f * bsp[c];
    }
}

// ---------------------------------------------------------------------------
// Fused main kernel: one WG per (scene, i-quad). M = 64 rows (r = i_loc*16 + j).
// Xs  : bf16 [64][128], row stride 256 B, XOR-swizzled (byte ^= (row&7)<<4)
// Y1s : bf16 [64][512], row stride 1024 B, same swizzle. Total LDS = 80 KB.
// A-frag (16x16x32): lane holds A[m = l&15][k = (l>>4)*8 + j] -> ds_read_b128.
// C/D: lane holds D[row = (l>>4)*4 + reg][col = l&15].
// ---------------------------------------------------------------------------
__global__ __launch_bounds__(256, 2) void fused_kernel(
    const float* __restrict__ hst,   // (1,B,H) fp32
    const float* __restrict__ epos,  // (B,2) fp32
    const unsigned char* __restrict__ ws,
    float* __restrict__ out)         // (4096,1024) fp32
{
    __shared__ unsigned char smem[81920];
    // [0,16384)      Xs
    // [16384,81920)  Y1s  (first 128 B double as pos[] scratch during X stage)
    float* posf = (float*)(smem + 16384);

    const float* A1  = (const float*)(ws + A1_OFF);
    const float* C1  = (const float*)(ws + C1_OFF);
    const float* A2  = (const float*)(ws + A2_OFF);
    const float* C2  = (const float*)(ws + C2_OFF);
    const float* SWb = (const float*)(ws + SW_OFF);

    const int s    = blockIdx.x >> 2;
    const int iblk = blockIdx.x & 3;
    const int tid  = threadIdx.x;
    const int w    = tid >> 6;
    const int l    = tid & 63;
    const int quad = l >> 4;
    const int lrow = l & 15;

    if (tid < 32) posf[tid] = epos[s * 32 + tid];
    __syncthreads();

    // ---- Stage X into LDS (bf16, swizzled), 0.05 already folded into SWb/h ----
    #pragma unroll
    for (int it = 0; it < 16; ++it) {
        int e = tid + it * 256;
        int r = e >> 6, p = e & 63;           // global col pair c = 2p
        int j = r & 15, il = r >> 4;
        int i = iblk * 4 + il;
        float v0, v1;
        if (p < 32) {
            int c0 = p * 2;
            float rx = posf[2 * j]     - posf[2 * i];
            float ry = posf[2 * j + 1] - posf[2 * i + 1];
            v0 = fmaf(rx, SWb[c0],     fmaf(ry, SWb[64 + c0],     SWb[128 + c0]));
            v1 = fmaf(rx, SWb[c0 + 1], fmaf(ry, SWb[64 + c0 + 1], SWb[128 + c0 + 1]));
        } else {
            const float* hp = hst + (s * 16 + j) * 64 + (p * 2 - 64);
            v0 = 0.05f * hp[0];
            v1 = 0.05f * hp[1];
        }
        unsigned int pk = (unsigned)f2bf(v0) | ((unsigned)f2bf(v1) << 16);
        int off = (p * 4) ^ ((r & 7) << 4);
        *(unsigned int*)(smem + r * 256 + off) = pk;
    }
    __syncthreads();

    const f32x4 fzero = {0.f, 0.f, 0.f, 0.f};

    // ---- mm1: Y1[64x512] = relu(bn(X @ Wp1)); wave w covers cols [w*128, w*128+128) ----
    #pragma unroll 1
    for (int g = 0; g < 2; ++g) {
        f32x4 acc[4][4];
        #pragma unroll
        for (int rt = 0; rt < 4; ++rt)
            #pragma unroll
            for (int ct = 0; ct < 4; ++ct) acc[rt][ct] = fzero;

        #pragma unroll
        for (int ks = 0; ks < 4; ++ks) {
            bf16x8 af[4];
            #pragma unroll
            for (int rt = 0; rt < 4; ++rt) {
                int row = rt * 16 + lrow;
                int off = (ks * 64 + quad * 16) ^ ((row & 7) << 4);
                af[rt] = *(const bf16x8*)(smem + row * 256 + off);
            }
            bf16x8 bfr[4];
            #pragma unroll
            for (int ct = 0; ct < 4; ++ct) {
                int nt = (w << 3) + (g << 2) + ct;
                bfr[ct] = *(const bf16x8*)(ws + BP1_OFF + (((nt * 4 + ks) * 64 + l) << 4));
            }
            #pragma unroll
            for (int rt = 0; rt < 4; ++rt)
                #pragma unroll
                for (int ct = 0; ct < 4; ++ct)
                    acc[rt][ct] = __builtin_amdgcn_mfma_f32_16x16x32_bf16(af[rt], bfr[ct], acc[rt][ct], 0, 0, 0);
        }
        // epilogue: bn+relu -> bf16 -> Y1s (swizzled)
        #pragma unroll
        for (int ct = 0; ct < 4; ++ct) {
            int nt  = (w << 3) + (g << 2) + ct;
            int col = nt * 16 + lrow;
            float a1 = A1[col], c1 = C1[col];
            #pragma unroll
            for (int rt = 0; rt < 4; ++rt) {
                #pragma unroll
                for (int reg = 0; reg < 4; ++reg) {
                    int row = rt * 16 + quad * 4 + reg;
                    float y = fmaxf(fmaf(acc[rt][ct][reg], a1, c1), 0.f);
                    int off = (col * 2) ^ ((row & 7) << 4);
                    *(unsigned short*)(smem + 16384 + row * 1024 + off) = f2bf(y);
                }
            }
        }
    }
    __syncthreads();

    // ---- mm2: Y2[64x1024] = relu(bn(Y1 @ Wp2)); max over j; wave w covers cols [w*256, ...) ----
    #pragma unroll 1
    for (int g = 0; g < 4; ++g) {
        f32x4 acc[4][4];
        #pragma unroll
        for (int rt = 0; rt < 4; ++rt)
            #pragma unroll
            for (int ct = 0; ct < 4; ++ct) acc[rt][ct] = fzero;

        #pragma unroll
        for (int ks = 0; ks < 16; ++ks) {
            bf16x8 af[4];
            #pragma unroll
            for (int rt = 0; rt < 4; ++rt) {
                int row = rt * 16 + lrow;
                int off = (ks * 64 + quad * 16) ^ ((row & 7) << 4);
                af[rt] = *(const bf16x8*)(smem + 16384 + row * 1024 + off);
            }
            bf16x8 bfr[4];
            #pragma unroll
            for (int ct = 0; ct < 4; ++ct) {
                int nt = (w << 4) + (g << 2) + ct;
                bfr[ct] = *(const bf16x8*)(ws + BP2_OFF + (((nt * 16 + ks) * 64 + l) << 4));
            }
            #pragma unroll
            for (int rt = 0; rt < 4; ++rt)
                #pragma unroll
                for (int ct = 0; ct < 4; ++ct)
                    acc[rt][ct] = __builtin_amdgcn_mfma_f32_16x16x32_bf16(af[rt], bfr[ct], acc[rt][ct], 0, 0, 0);
        }
        // epilogue: bn+relu, then max over j (rows within rowtile), store fp32
        #pragma unroll
        for (int ct = 0; ct < 4; ++ct) {
            int nt  = (w << 4) + (g << 2) + ct;
            int col = nt * 16 + lrow;
            float a2 = A2[col], c2 = C2[col];
            #pragma unroll
            for (int rt = 0; rt < 4; ++rt) {   // rt == i_loc; j = quad*4 + reg
                float v0 = fmaxf(fmaf(acc[rt][ct][0], a2, c2), 0.f);
                float v1 = fmaxf(fmaf(acc[rt][ct][1], a2, c2), 0.f);
                float v2 = fmaxf(fmaf(acc[rt][ct][2], a2, c2), 0.f);
                float v3 = fmaxf(fmaf(acc[rt][ct][3], a2, c2), 0.f);
                float v = fmaxf(fmaxf(v0, v1), fmaxf(v2, v3));
                v = fmaxf(v, __shfl_xor(v, 16, 64));
                v = fmaxf(v, __shfl_xor(v, 32, 64));
                if (l < 16) {
                    int orow = s * 16 + iblk * 4 + rt;
                    out[orow * 1024 + col] = v;
                }
            }
        }
    }
}

extern "C" void kernel_launch(void* const* d_in, const int* in_sizes, int n_in,
                              void* d_out, int out_size, void* d_ws, size_t ws_size,
                              hipStream_t stream) {
    const float* hst  = (const float*)d_in[0];   // h_states (1,B,H)
    const float* epos = (const float*)d_in[1];   // end_pos (B,2)
    const float* Wsp  = (const float*)d_in[4];
    const float* bsp  = (const float*)d_in[5];
    const float* Wp1  = (const float*)d_in[20];
    const float* bp1  = (const float*)d_in[21];
    const float* gp1  = (const float*)d_in[22];
    const float* btp1 = (const float*)d_in[23];
    const float* mp1  = (const float*)d_in[24];
    const float* vp1  = (const float*)d_in[25];
    const float* Wp2  = (const float*)d_in[26];
    const float* bp2  = (const float*)d_in[27];
    const float* gp2  = (const float*)d_in[28];
    const float* btp2 = (const float*)d_in[29];
    const float* mp2  = (const float*)d_in[30];
    const float* vp2  = (const float*)d_in[31];
    unsigned char* ws = (unsigned char*)d_ws;
    float* out = (float*)d_out;

    // prep: 65536 + 8192 + 1024 + 512 + 64 = 75328 threads
    prep_kernel<<<295, 256, 0, stream>>>(Wsp, bsp, Wp1, bp1, gp1, btp1, mp1, vp1,
                                         Wp2, bp2, gp2, btp2, mp2, vp2, ws);
    // main: 256 scenes * 4 i-quads
    fused_kernel<<<1024, 256, 0, stream>>>(hst, epos, ws, out);
}